// Round 1
// baseline (191.770 us; speedup 1.0000x reference)
//
#include <hip/hip_runtime.h>
#include <hip/hip_bf16.h>
#include <stdint.h>

// Problem constants (from reference): B=4096, D=768, N=8192, S=4
#define Bdim 4096
#define Ddim 768
#define Ndim 8192
#define Sdim 4

typedef __attribute__((ext_vector_type(8))) short short8;
typedef __attribute__((ext_vector_type(4))) float floatx4;

// fp32 -> bf16 round-to-nearest-even, as raw ushort
__device__ inline unsigned short f2bf(float f) {
  unsigned u = __builtin_bit_cast(unsigned, f);
  unsigned r = (u + 0x7fffu + ((u >> 16) & 1u)) >> 16;
  return (unsigned short)r;
}
__device__ inline float bf2f(unsigned short s) {
  return __builtin_bit_cast(float, (unsigned)s << 16);
}

// async global->LDS, 16B per lane (global_load_lds_dwordx4)
__device__ inline void async_copy16(const void* g, void* l) {
  __builtin_amdgcn_global_load_lds(
      (__attribute__((address_space(1))) void*)(g),
      (__attribute__((address_space(3))) void*)(l),
      16, 0, 0);
}

// ---------------------------------------------------------------------------
// Kernel 1: fp32 -> bf16 conversion of batch_x and cat; zero the stats region
// stats = [s4 (B) | denom (B) | numer (S*B)] = 6*B floats, contiguous
// ---------------------------------------------------------------------------
__global__ void convert_kernel(const float* __restrict__ x,
                               const float* __restrict__ cat,
                               unsigned short* __restrict__ xb,
                               unsigned short* __restrict__ catb,
                               float* __restrict__ stats) {
  int gid = blockIdx.x * blockDim.x + threadIdx.x;
  int stride = gridDim.x * blockDim.x;
  const int nx4 = (Bdim * Ddim) / 4;
  const int nc4 = (Ndim * Ddim) / 4;
  for (int i = gid; i < nx4; i += stride) {
    float4 v = ((const float4*)x)[i];
    ushort4 o;
    o.x = f2bf(v.x); o.y = f2bf(v.y); o.z = f2bf(v.z); o.w = f2bf(v.w);
    ((ushort4*)xb)[i] = o;
  }
  for (int i = gid; i < nc4; i += stride) {
    float4 v = ((const float4*)cat)[i];
    ushort4 o;
    o.x = f2bf(v.x); o.y = f2bf(v.y); o.z = f2bf(v.z); o.w = f2bf(v.w);
    ((ushort4*)catb)[i] = o;
  }
  if (gid < 6 * Bdim) stats[gid] = 0.0f;
}

// ---------------------------------------------------------------------------
// Kernel 2: bf16 MFMA GEMM  con[n,b] = sum_k cat[n,k]*x[b,k]
// m97 structure: 128x128 tile, BK=32, 4 waves of 64x64, 16x16x32 MFMA,
// global_load_lds width 16. Output stored as bf16 [Ndim, Bdim].
// ---------------------------------------------------------------------------
__global__ __launch_bounds__(256) void gemm_bt_kernel(
    const unsigned short* __restrict__ A,   // cat bf16 [Ndim, Ddim]
    const unsigned short* __restrict__ Bm,  // x   bf16 [Bdim, Ddim]
    unsigned short* __restrict__ C) {       // con bf16 [Ndim, Bdim]
  __shared__ unsigned short As[128 * 32];  // 8 KB
  __shared__ unsigned short Bs[128 * 32];  // 8 KB

  const int tid = threadIdx.x;
  const int wave = tid >> 6;
  const int lane = tid & 63;
  const int quad = lane >> 4;
  const int l16 = lane & 15;
  const int wm = (wave & 1) * 64;
  const int wn = (wave >> 1) * 64;
  const int m0 = blockIdx.x * 128;
  const int n0 = blockIdx.y * 128;

  floatx4 acc[4][4];
#pragma unroll
  for (int i = 0; i < 4; ++i)
#pragma unroll
    for (int j = 0; j < 4; ++j) acc[i][j] = (floatx4){0.f, 0.f, 0.f, 0.f};

  // staging: 512 chunks of 16B per tile; chunk c -> row c>>2, col (c&3)*8
  // LDS dest offset = chunk*16 = (wave*1024 + lane*16) [+4096] -> satisfies
  // the wave-uniform-base + lane*16 constraint of global_load_lds.
  const int c0 = tid, c1 = tid + 256;
  const int r0 = c0 >> 2, col0 = (c0 & 3) * 8;
  const int r1 = c1 >> 2, col1 = (c1 & 3) * 8;
  const unsigned short* a0 = A + (size_t)(m0 + r0) * Ddim + col0;
  const unsigned short* a1 = A + (size_t)(m0 + r1) * Ddim + col1;
  const unsigned short* b0 = Bm + (size_t)(n0 + r0) * Ddim + col0;
  const unsigned short* b1 = Bm + (size_t)(n0 + r1) * Ddim + col1;

  for (int k0 = 0; k0 < Ddim; k0 += 32) {
    async_copy16(a0 + k0, (char*)As + c0 * 16);
    async_copy16(a1 + k0, (char*)As + c1 * 16);
    async_copy16(b0 + k0, (char*)Bs + c0 * 16);
    async_copy16(b1 + k0, (char*)Bs + c1 * 16);
    __syncthreads();  // drains vmcnt before barrier

    short8 af[4], bf[4];
#pragma unroll
    for (int mi = 0; mi < 4; ++mi)
      af[mi] = *(const short8*)(As + (wm + mi * 16 + l16) * 32 + quad * 8);
#pragma unroll
    for (int ni = 0; ni < 4; ++ni)
      bf[ni] = *(const short8*)(Bs + (wn + ni * 16 + l16) * 32 + quad * 8);
#pragma unroll
    for (int mi = 0; mi < 4; ++mi)
#pragma unroll
      for (int ni = 0; ni < 4; ++ni)
        acc[mi][ni] = __builtin_amdgcn_mfma_f32_16x16x32_bf16(
            af[mi], bf[ni], acc[mi][ni], 0, 0, 0);
    __syncthreads();
  }

  // C/D layout (16x16): col = lane&15, row = quad*4 + reg  [m89-verified]
#pragma unroll
  for (int mi = 0; mi < 4; ++mi)
#pragma unroll
    for (int ni = 0; ni < 4; ++ni) {
      int row = m0 + wm + mi * 16 + quad * 4;
      int col = n0 + wn + ni * 16 + l16;
#pragma unroll
      for (int r = 0; r < 4; ++r)
        C[(size_t)(row + r) * Bdim + col] = f2bf(acc[mi][ni][r]);
    }
}

// ---------------------------------------------------------------------------
// Kernel 3: s4[b] += sum over a 128-row chunk of con[n,b]^4
// ---------------------------------------------------------------------------
__global__ void pow4_kernel(const unsigned short* __restrict__ con,
                            float* __restrict__ s4) {
  int b = blockIdx.x * 256 + threadIdx.x;
  int n0 = blockIdx.y * 128;
  const unsigned short* p = con + (size_t)n0 * Bdim + b;
  float acc = 0.f;
#pragma unroll 4
  for (int i = 0; i < 128; ++i) {
    float c = bf2f(p[(size_t)i * Bdim]);
    float c2 = c * c;
    acc += c2 * c2;
  }
  atomicAdd(&s4[b], acc);
}

// ---------------------------------------------------------------------------
// Kernel 4: denom[b] += sum exp(con/norm4); numer[s,b] += y-masked sum.
// norm4 >= max|con| so logits are in [-1,1]: no max-subtraction needed
// (softmax is shift-invariant; reference result identical).
// ---------------------------------------------------------------------------
__global__ void expsum_kernel(const unsigned short* __restrict__ con,
                              const float* __restrict__ s4,
                              const int* __restrict__ y,
                              float* __restrict__ denom,
                              float* __restrict__ numer) {
  int b = blockIdx.x * 256 + threadIdx.x;
  int n0 = blockIdx.y * 128;
  int src = n0 / (Ndim / Sdim);
  float nrm = sqrtf(sqrtf(s4[b]));
  float inv = 1.0f / fmaxf(nrm, 1e-12f);
  const unsigned short* p = con + (size_t)n0 * Bdim + b;
  float dsum = 0.f, nsum = 0.f;
#pragma unroll 4
  for (int i = 0; i < 128; ++i) {
    float e = __expf(bf2f(p[(size_t)i * Bdim]) * inv);
    dsum += e;
    nsum += e * (float)y[n0 + i];
  }
  atomicAdd(&denom[b], dsum);
  atomicAdd(&numer[src * Bdim + b], nsum);
}

// ---------------------------------------------------------------------------
// Kernel 5: one wave per batch row b: theta_s = exp(x[b].phi[s]) (fp32,
// shuffle-reduced), then out[b] = sigmoid(sum_s numer[s,b]*theta_s/denom + bias)
// ---------------------------------------------------------------------------
__global__ void finalize_kernel(const float* __restrict__ x,
                                const float* __restrict__ phi,
                                const float* __restrict__ denom,
                                const float* __restrict__ numer,
                                const float* __restrict__ bias,
                                float* __restrict__ out) {
  int gw = (blockIdx.x * blockDim.x + threadIdx.x) >> 6;
  int lane = threadIdx.x & 63;
  if (gw >= Bdim) return;
  const float* xr = x + (size_t)gw * Ddim;
  float a0 = 0.f, a1 = 0.f, a2 = 0.f, a3 = 0.f;
  for (int d = lane; d < Ddim; d += 64) {
    float xv = xr[d];
    a0 = fmaf(xv, phi[d], a0);
    a1 = fmaf(xv, phi[Ddim + d], a1);
    a2 = fmaf(xv, phi[2 * Ddim + d], a2);
    a3 = fmaf(xv, phi[3 * Ddim + d], a3);
  }
#pragma unroll
  for (int off = 32; off > 0; off >>= 1) {
    a0 += __shfl_down(a0, off);
    a1 += __shfl_down(a1, off);
    a2 += __shfl_down(a2, off);
    a3 += __shfl_down(a3, off);
  }
  if (lane == 0) {
    float s = numer[gw] * __expf(a0) + numer[Bdim + gw] * __expf(a1) +
              numer[2 * Bdim + gw] * __expf(a2) + numer[3 * Bdim + gw] * __expf(a3);
    s = s / denom[gw];
    float z = s + bias[0];
    out[gw] = 1.0f / (1.0f + __expf(-z));
  }
}

// ---------------------------------------------------------------------------
// Workspace layout (bytes):
//   catb  : Ndim*Ddim*2   = 12,582,912
//   xb    : Bdim*Ddim*2   =  6,291,456
//   con   : Ndim*Bdim*2   = 67,108,864
//   stats : 6*Bdim*4      =     98,304   (s4 | denom | numer)
//   total ≈ 86 MB
// ---------------------------------------------------------------------------
extern "C" void kernel_launch(void* const* d_in, const int* in_sizes, int n_in,
                              void* d_out, int out_size, void* d_ws,
                              size_t ws_size, hipStream_t stream) {
  const float* batch_x = (const float*)d_in[0];
  const float* cat = (const float*)d_in[1];
  const int* y = (const int*)d_in[2];
  const float* phi = (const float*)d_in[3];
  const float* bias = (const float*)d_in[4];
  float* out = (float*)d_out;

  char* ws = (char*)d_ws;
  unsigned short* catb = (unsigned short*)ws;
  unsigned short* xb = catb + (size_t)Ndim * Ddim;
  unsigned short* con = xb + (size_t)Bdim * Ddim;
  float* stats = (float*)(con + (size_t)Ndim * Bdim);
  float* s4 = stats;
  float* denom = s4 + Bdim;
  float* numer = denom + Bdim;  // Sdim * Bdim

  convert_kernel<<<2048, 256, 0, stream>>>(batch_x, cat, xb, catb, stats);

  dim3 g2(Ndim / 128, Bdim / 128);
  gemm_bt_kernel<<<g2, 256, 0, stream>>>(catb, xb, con);

  dim3 g3(Bdim / 256, Ndim / 128);
  pow4_kernel<<<g3, 256, 0, stream>>>(con, s4);
  expsum_kernel<<<g3, 256, 0, stream>>>(con, s4, y, denom, numer);

  finalize_kernel<<<1024, 256, 0, stream>>>(batch_x, phi, denom, numer, bias, out);
}